// Round 10
// baseline (367.848 us; speedup 1.0000x reference)
//
#include <hip/hip_runtime.h>

#define N_NODES 50000
#define N_EDGES 800000
#define DIM     200
#define NBLK    100   // B blocks of S=2
#define NRELS   230
#define NB_SCAN 196   // ceil(N_NODES/256)
#define KPAD    224   // feature-row stride (bf16 buffers)
#define KPN     256   // gemm output-column pad (8 nt of 32)
#define NROWPAD 50048
#define NFRAG8  (8 * 14 * 64)   // fragment-packed weights: 8 nt x 14 ks x 64 lanes (x8 bf16)

typedef __attribute__((ext_vector_type(8)))  short short8;
typedef __attribute__((ext_vector_type(16))) float f32x16;

__device__ __forceinline__ unsigned short f2bf(float f) {
    unsigned u = __float_as_uint(f);
    u += 0x7fffu + ((u >> 16) & 1u);        // RNE (inputs finite)
    return (unsigned short)(u >> 16);
}

__device__ __forceinline__ float bflo(unsigned u) { return __uint_as_float(u << 16); }
__device__ __forceinline__ float bfhi(unsigned u) { return __uint_as_float(u & 0xffff0000u); }
__device__ __forceinline__ float b2f(unsigned short u) { return __uint_as_float((unsigned)u << 16); }

__device__ __forceinline__ float tanh_fast(float x) {
    float xa = fminf(fmaxf(x, -15.0f), 15.0f);
    float e = __expf(2.0f * xa);
    return (e - 1.0f) / (e + 1.0f);
}

__device__ __forceinline__ int uread(int v, int l) {
    return __builtin_amdgcn_readlane(v, l);
}

// ---- bf16 dot2: 1 instruction for a0*b0+a1*b1+c when available
#if __has_builtin(__builtin_amdgcn_fdot2_f32_bf16)
typedef __bf16 bf16x2 __attribute__((ext_vector_type(2)));
__device__ __forceinline__ float dot2bf(unsigned a, unsigned b, float c) {
    return __builtin_amdgcn_fdot2_f32_bf16(
        __builtin_bit_cast(bf16x2, a), __builtin_bit_cast(bf16x2, b), c, false);
}
#define CMP(XU, WU, M0, M1, M2, M3)                                     \
    { M0 = dot2bf(XU.x, WU.x, M0); M1 = dot2bf(XU.x, WU.y, M1);         \
      M2 = dot2bf(XU.y, WU.z, M2); M3 = dot2bf(XU.y, WU.w, M3); }
#else
#define CMP(XU, WU, M0, M1, M2, M3)                                     \
    { float x0 = bflo(XU.x), x1 = bfhi(XU.x);                           \
      float x2 = bflo(XU.y), x3 = bfhi(XU.y);                           \
      M0 += x0 * bflo(WU.x) + x1 * bfhi(WU.x);                          \
      M1 += x0 * bflo(WU.y) + x1 * bfhi(WU.y);                          \
      M2 += x2 * bflo(WU.z) + x3 * bfhi(WU.z);                          \
      M3 += x2 * bflo(WU.w) + x3 * bfhi(WU.w); }
#endif

// LDS swizzle for 512B-stride rows, 16B-granular access
#define SWZ5(rr, off) ((unsigned)((rr) * 512 + (off)) ^ ((unsigned)((rr) & 15) << 4))

// ---------------------------------------------------------------- CSR build
__global__ void deg_int_kernel(const int* __restrict__ dst, int* __restrict__ degi) {
    int e = blockIdx.x * blockDim.x + threadIdx.x;
    if (e < N_EDGES) atomicAdd(&degi[dst[e]], 1);
}

__global__ __launch_bounds__(256) void scanA(const int* __restrict__ degi,
                                             int* __restrict__ pos,
                                             int* __restrict__ bsum) {
    __shared__ int tmp[256];
    int t = threadIdx.x;
    int g = blockIdx.x * 256 + t;
    int v = (g < N_NODES) ? degi[g] : 0;
    tmp[t] = v;
    __syncthreads();
    for (int off = 1; off < 256; off <<= 1) {
        int xv = (t >= off) ? tmp[t - off] : 0;
        __syncthreads();
        tmp[t] += xv;
        __syncthreads();
    }
    if (g < N_NODES) pos[g] = tmp[t] - v;
    if (t == 255) bsum[blockIdx.x] = tmp[255];
}

// fused scanB+scanC: every block redundantly scans bsum (196 els), then adds its prefix
__global__ __launch_bounds__(256) void scanC2(int* __restrict__ pos, const int* __restrict__ bsum) {
    __shared__ int tmp[256];
    __shared__ int excl[256];
    int t = threadIdx.x;
    int v = (t < NB_SCAN) ? bsum[t] : 0;
    tmp[t] = v;
    __syncthreads();
    for (int off = 1; off < 256; off <<= 1) {
        int xv = (t >= off) ? tmp[t - off] : 0;
        __syncthreads();
        tmp[t] += xv;
        __syncthreads();
    }
    excl[t] = tmp[t] - v;
    __syncthreads();
    int add = excl[blockIdx.x];
    int g = blockIdx.x * 256 + t;
    if (g < N_NODES) pos[g] += add;
}

// fill: se[slot] = src | (etype << 16)
__global__ void fill_kernel(const int* __restrict__ src, const int* __restrict__ dst,
                            const int* __restrict__ et,
                            int* __restrict__ pos, int* __restrict__ se) {
    int e = blockIdx.x * blockDim.x + threadIdx.x;
    if (e < N_EDGES) {
        int d = dst[e];
        int slot = atomicAdd(&pos[d], 1);
        se[slot] = src[e] | (et[e] << 16);
    }
}

// ---------------------------------------------------------------- fused feature prep (node_feat->hb, dyn_emb->h0b)
__global__ void prep_feat(const float* __restrict__ x, const float* __restrict__ de,
                          unsigned short* __restrict__ hb, unsigned short* __restrict__ h0b) {
    const int HALF = NROWPAD * (KPAD / 2);
    int idx = blockIdx.x * blockDim.x + threadIdx.x;
    if (idx >= 2 * HALF) return;
    const float* src = (idx < HALF) ? x : de;
    unsigned short* dstp = (idx < HALF) ? hb : h0b;
    int j = (idx < HALF) ? idx : idx - HALF;
    int row = j / (KPAD / 2), cu = j % (KPAD / 2);
    unsigned pk = 0;
    if (row < N_NODES && cu < 100) {
        float2 v = *(const float2*)(src + (size_t)row * DIM + cu * 2);
        pk = (unsigned)f2bf(v.x) | ((unsigned)f2bf(v.y) << 16);
    }
    *(unsigned*)(dstp + (size_t)j * 2) = pk;
}

// fused relation-weight prep: w1->w1b, w2->w2b (dot2 column pairs)
__global__ void prep_wbs(const float* __restrict__ w1, const float* __restrict__ w2,
                         unsigned short* __restrict__ w1b, unsigned short* __restrict__ w2b) {
    const int HALF = NRELS * NBLK;
    int idx = blockIdx.x * blockDim.x + threadIdx.x;
    if (idx >= 2 * HALF) return;
    const float* w = (idx < HALF) ? w1 : w2;
    unsigned short* o = (idx < HALF) ? w1b : w2b;
    int j = (idx < HALF) ? idx : idx - HALF;
    float4 v = *(const float4*)(w + (size_t)j * 4);  // w00,w01,w10,w11
    unsigned c0 = (unsigned)f2bf(v.x) | ((unsigned)f2bf(v.z) << 16);
    unsigned c1 = (unsigned)f2bf(v.y) | ((unsigned)f2bf(v.w) << 16);
    *(uint2*)(o + (size_t)j * 4) = make_uint2(c0, c1);
}

// fused frag prep: sec0 = fragT(loop_w1)->w1f ; sec1 = frag(W_ih)->wihf ; sec2 = frag(W_hh)->whhf
__global__ void prep_frags(const float* __restrict__ lw1, const float* __restrict__ wih,
                           const float* __restrict__ whh,
                           unsigned short* __restrict__ w1f, unsigned short* __restrict__ wihf,
                           unsigned short* __restrict__ whhf) {
    int idx = blockIdx.x * blockDim.x + threadIdx.x;
    if (idx >= 3 * NFRAG8) return;
    int sec = idx / NFRAG8, f = idx % NFRAG8;
    const float* w = (sec == 0) ? lw1 : (sec == 1) ? wih : whh;
    unsigned short* o = (sec == 0) ? w1f : (sec == 1) ? wihf : whhf;
    int l = f & 63;
    int ks = (f >> 6) % 14;
    int nt = f / (14 * 64);
    int n  = nt * 32 + (l & 31);
    int k0 = ks * 16 + (l >> 5) * 8;
    unsigned short v[8];
    #pragma unroll
    for (int j = 0; j < 8; ++j) {
        int k = k0 + j;
        float val = 0.0f;
        if (n < DIM && k < DIM)
            val = (sec == 0) ? w[k * DIM + n] : w[n * DIM + k];
        v[j] = f2bf(val);
    }
    *(uint4*)(o + (size_t)f * 8) = *(uint4*)v;
}

// M = w2 @ W_ih^T computed directly into fragment layout (x@M form), + biasv
// M[k][n] = dot(loop_w2 row k, W_ih row n); biasv[n] = dot(b2, W_ih row n) + b_ih[n] + b_hh[n]
__global__ void prep_Mf(const float* __restrict__ w2, const float* __restrict__ wih,
                        const float* __restrict__ b2, const float* __restrict__ b_ih,
                        const float* __restrict__ b_hh,
                        unsigned short* __restrict__ Mf, float* __restrict__ biasv) {
    int idx = blockIdx.x * blockDim.x + threadIdx.x;
    if (idx < NFRAG8) {
        int l = idx & 63;
        int ks = (idx >> 6) % 14;
        int nt = idx / (14 * 64);
        int n  = nt * 32 + (l & 31);
        int k0 = ks * 16 + (l >> 5) * 8;
        unsigned short v[8];
        #pragma unroll
        for (int j = 0; j < 8; ++j) {
            int k = k0 + j;
            float s = 0.0f;
            if (n < DIM && k < DIM) {
                const float* wr = w2 + (size_t)k * DIM;
                const float* ir = wih + (size_t)n * DIM;
                for (int q = 0; q < DIM; ++q) s += wr[q] * ir[q];
            }
            v[j] = f2bf(s);
        }
        *(uint4*)(Mf + (size_t)idx * 8) = *(uint4*)v;
    } else if (idx < NFRAG8 + KPN) {
        int n = idx - NFRAG8;
        float s = 0.0f;
        if (n < DIM) {
            const float* ir = wih + (size_t)n * DIM;
            for (int q = 0; q < DIM; ++q) s += b2[q] * ir[q];
            s += b_ih[n] + b_hh[n];
        }
        biasv[n] = s;
    }
}

// ---------------------------------------------------------------- gather: 2 blocks/lane, 4-edge pipeline
// lane l<50 owns blocks {2l, 2l+1}; lanes 50-55 zero-fill pad cols 200..223 of agg.
#define GL(QQ, XU, WU)                                                  \
    { int p_ = uread(sv, (QQ)); int s_ = p_ & 0xffff; int r_ = p_ >> 16;\
      XU = *(const uint2*)(x  + (size_t)s_ * KPAD + xoff);              \
      WU = *(const uint4*)(wb + (size_t)r_ * (NBLK * 4) + woff); }

__global__ __launch_bounds__(256) void gatherB(
        const unsigned short* __restrict__ x,    // [NROWPAD][KPAD] bf16
        const int*   __restrict__ se,            // packed (src | et<<16), CSR order
        const int*   __restrict__ endpos,
        const int*   __restrict__ degi,
        const unsigned short* __restrict__ wb,   // [R][NBLK][4] bf16 (column pairs)
        unsigned short* __restrict__ agg) {      // [NROWPAD][KPAD] bf16
    int node = (blockIdx.x * blockDim.x + threadIdx.x) >> 6;
    int lane = threadIdx.x & 63;
    if (node >= N_NODES) return;
    int deg = __builtin_amdgcn_readfirstlane(degi[node]);
    const bool act = (lane < 50);
    int cl   = act ? lane : 49;                  // clamp idle lanes to valid addrs
    int xoff = 4 * cl;                           // ushort units (8B per lane)
    int woff = 8 * cl;                           // ushort units (16B per lane)

    if (deg == 0) {
        if (lane < 56) *(uint2*)(agg + (size_t)node * KPAD + 4 * lane) = make_uint2(0u, 0u);
        return;
    }
    int end   = __builtin_amdgcn_readfirstlane(endpos[node]);
    int start = end - deg;

    float m0A = 0.f, m1A = 0.f, m2A = 0.f, m3A = 0.f;
    float m0B = 0.f, m1B = 0.f, m2B = 0.f, m3B = 0.f;

    for (int base = start; base < end; base += 64) {
        int cnt = end - base; if (cnt > 64) cnt = 64;
        int sv = se[base + (lane < cnt ? lane : cnt - 1)];

        uint2 X0 = {0,0}, X1 = {0,0}, X2 = {0,0}, X3 = {0,0};
        uint4 W0 = {0,0,0,0}, W1 = {0,0,0,0}, W2 = {0,0,0,0}, W3 = {0,0,0,0};

        GL(0, X0, W0);
        if (cnt > 1) GL(1, X1, W1);
        if (cnt > 2) GL(2, X2, W2);

        for (int q = 0; q < cnt; q += 4) {
            if (q + 3 < cnt) GL(q + 3, X3, W3);
            CMP(X0, W0, m0A, m1A, m2A, m3A);
            if (q + 4 < cnt) GL(q + 4, X0, W0);
            if (q + 1 < cnt) CMP(X1, W1, m0B, m1B, m2B, m3B);
            if (q + 5 < cnt) GL(q + 5, X1, W1);
            if (q + 2 < cnt) CMP(X2, W2, m0A, m1A, m2A, m3A);
            if (q + 6 < cnt) GL(q + 6, X2, W2);
            if (q + 3 < cnt) CMP(X3, W3, m0B, m1B, m2B, m3B);
        }
    }
    float nrm = 1.0f / (float)deg;
    uint2 ov = make_uint2(0u, 0u);
    if (act) {
        ov.x = (unsigned)f2bf((m0A + m0B) * nrm) | ((unsigned)f2bf((m1A + m1B) * nrm) << 16);
        ov.y = (unsigned)f2bf((m2A + m2B) * nrm) | ((unsigned)f2bf((m3A + m3B) * nrm) << 16);
    }
    if (lane < 56) *(uint2*)(agg + (size_t)node * KPAD + 4 * lane) = ov;
}

// ---------------------------------------------------------------- GEMM1: hb = bf16(tanh(agg1 + x@loop_w1 + b1))
// In-place: xb and hb are the SAME buffer. agg1 is bf16 KPAD-strided.
__global__ __launch_bounds__(256) void gemm1_kernel(
        unsigned short* xb_hb,
        const unsigned short* __restrict__ agg1,  // [NROWPAD][KPAD] bf16
        const float* __restrict__ b1,
        const unsigned short* __restrict__ w1f) {
    __shared__ __align__(16) unsigned short s_a[32 * KPN];
    int row0 = blockIdx.x * 32;
    int tid = threadIdx.x;
    for (int i = tid; i < 32 * 32; i += 256) {
        int rr = i >> 5, ch = i & 31;
        uint4 v = {0, 0, 0, 0};
        if (ch < 28) v = *(const uint4*)(xb_hb + (size_t)(row0 + rr) * KPAD + ch * 8);
        *(uint4*)((char*)s_a + SWZ5(rr, ch * 16)) = v;
    }
    __syncthreads();

    int l = tid & 63, wv = tid >> 6;
    int rl = l & 31, hl = l >> 5;
    int ntlo = wv * 2;
    const unsigned short* wb = w1f + (size_t)(ntlo * 14) * 512 + l * 8;

    f32x16 acc0 = {}, acc1 = {};
    short8 aC  = *(const short8*)((const char*)s_a + SWZ5(rl, (hl * 8) * 2));
    short8 b0C = *(const short8*)(wb);
    short8 b1C = *(const short8*)(wb + 14 * 512);
    #pragma unroll
    for (int ks = 0; ks < 13; ++ks) {
        short8 aN = {}, b0N = {}, b1N = {};
        if (ks < 12) {
            aN  = *(const short8*)((const char*)s_a + SWZ5(rl, ((ks + 1) * 16 + hl * 8) * 2));
            b0N = *(const short8*)(wb + (ks + 1) * 512);
            b1N = *(const short8*)(wb + 14 * 512 + (ks + 1) * 512);
        }
        acc0 = __builtin_amdgcn_mfma_f32_32x32x16_bf16(aC, b0C, acc0, 0, 0, 0);
        acc1 = __builtin_amdgcn_mfma_f32_32x32x16_bf16(aC, b1C, acc1, 0, 0, 0);
        aC = aN; b0C = b0N; b1C = b1N;
    }
    __syncthreads();   // all tile reads done before in-place overwrite

    #pragma unroll
    for (int t = 0; t < 2; ++t) {
        f32x16 ac = t ? acc1 : acc0;
        int gc = (ntlo + t) * 32 + rl;
        if (gc >= KPAD) continue;
        float bias = (gc < DIM) ? b1[gc] : 0.0f;
        #pragma unroll
        for (int r = 0; r < 16; ++r) {
            int gr = row0 + (r & 3) + 8 * (r >> 2) + 4 * hl;
            float v = 0.0f;
            if (gc < DIM && gr < N_NODES)
                v = ac[r] + b2f(agg1[(size_t)gr * KPAD + gc]) + bias;
            xb_hb[(size_t)gr * KPAD + gc] = f2bf(tanh_fast(v));
        }
    }
}

// ---------------------------------------------------------------- GEMM2 single-phase:
// out = tanh( hb@M + agg2@W_ih^T + h0@W_hh^T + biasv )
__global__ __launch_bounds__(256) void gemm2_kernel(
        const unsigned short* __restrict__ hb,
        const unsigned short* __restrict__ aggp,  // [NROWPAD][KPAD] bf16
        const unsigned short* __restrict__ h0b,
        const unsigned short* __restrict__ Mf,    // frag-packed M (x@M), 8 nt
        const unsigned short* __restrict__ wihf,  // frag-packed W_ih (x@w^T), 8 nt
        const unsigned short* __restrict__ whhf,  // frag-packed W_hh (x@w^T), 8 nt
        const float* __restrict__ biasv,          // [KPN]
        float* __restrict__ out) {
    __shared__ __align__(16) unsigned short s_h[32 * KPN];
    __shared__ __align__(16) unsigned short s_g[32 * KPN];
    __shared__ __align__(16) unsigned short s_e[32 * KPN];
    int row0 = blockIdx.x * 32;
    int tid = threadIdx.x;
    for (int i = tid; i < 32 * 32; i += 256) {
        int rr = i >> 5, ch = i & 31;
        uint4 vh = {0,0,0,0}, vg = {0,0,0,0}, ve = {0,0,0,0};
        if (ch < 28) {
            size_t off = (size_t)(row0 + rr) * KPAD + ch * 8;
            vh = *(const uint4*)(hb   + off);
            vg = *(const uint4*)(aggp + off);
            ve = *(const uint4*)(h0b  + off);
        }
        unsigned sw = SWZ5(rr, ch * 16);
        *(uint4*)((char*)s_h + sw) = vh;
        *(uint4*)((char*)s_g + sw) = vg;
        *(uint4*)((char*)s_e + sw) = ve;
    }
    __syncthreads();

    int l = tid & 63, wv = tid >> 6;
    int rl = l & 31, hl = l >> 5;
    int ntlo = wv * 2;
    const unsigned short* pm = Mf   + (size_t)(ntlo * 14) * 512 + l * 8;
    const unsigned short* pi = wihf + (size_t)(ntlo * 14) * 512 + l * 8;
    const unsigned short* ph = whhf + (size_t)(ntlo * 14) * 512 + l * 8;

    f32x16 a0 = {}, a1 = {};
    unsigned off0 = SWZ5(rl, (hl * 8) * 2);
    short8 hC  = *(const short8*)((const char*)s_h + off0);
    short8 gC  = *(const short8*)((const char*)s_g + off0);
    short8 eC  = *(const short8*)((const char*)s_e + off0);
    short8 m0C = *(const short8*)(pm);
    short8 m1C = *(const short8*)(pm + 14 * 512);
    short8 i0C = *(const short8*)(pi);
    short8 i1C = *(const short8*)(pi + 14 * 512);
    short8 h0C = *(const short8*)(ph);
    short8 h1C = *(const short8*)(ph + 14 * 512);
    #pragma unroll
    for (int ks = 0; ks < 13; ++ks) {
        short8 hN = {}, gN = {}, eN = {};
        short8 m0N = {}, m1N = {}, i0N = {}, i1N = {}, h0N = {}, h1N = {};
        if (ks < 12) {
            unsigned off = SWZ5(rl, ((ks + 1) * 16 + hl * 8) * 2);
            hN  = *(const short8*)((const char*)s_h + off);
            gN  = *(const short8*)((const char*)s_g + off);
            eN  = *(const short8*)((const char*)s_e + off);
            m0N = *(const short8*)(pm + (ks + 1) * 512);
            m1N = *(const short8*)(pm + 14 * 512 + (ks + 1) * 512);
            i0N = *(const short8*)(pi + (ks + 1) * 512);
            i1N = *(const short8*)(pi + 14 * 512 + (ks + 1) * 512);
            h0N = *(const short8*)(ph + (ks + 1) * 512);
            h1N = *(const short8*)(ph + 14 * 512 + (ks + 1) * 512);
        }
        a0 = __builtin_amdgcn_mfma_f32_32x32x16_bf16(hC, m0C, a0, 0, 0, 0);
        a0 = __builtin_amdgcn_mfma_f32_32x32x16_bf16(gC, i0C, a0, 0, 0, 0);
        a0 = __builtin_amdgcn_mfma_f32_32x32x16_bf16(eC, h0C, a0, 0, 0, 0);
        a1 = __builtin_amdgcn_mfma_f32_32x32x16_bf16(hC, m1C, a1, 0, 0, 0);
        a1 = __builtin_amdgcn_mfma_f32_32x32x16_bf16(gC, i1C, a1, 0, 0, 0);
        a1 = __builtin_amdgcn_mfma_f32_32x32x16_bf16(eC, h1C, a1, 0, 0, 0);
        hC = hN; gC = gN; eC = eN;
        m0C = m0N; m1C = m1N; i0C = i0N; i1C = i1N; h0C = h0N; h1C = h1N;
    }

    #pragma unroll
    for (int t = 0; t < 2; ++t) {
        f32x16 oc = t ? a1 : a0;
        int gc = (ntlo + t) * 32 + rl;
        if (gc >= DIM) continue;
        float bias = biasv[gc];
        #pragma unroll
        for (int r = 0; r < 16; ++r) {
            int gr = row0 + (r & 3) + 8 * (r >> 2) + 4 * hl;
            if (gr < N_NODES)
                out[(size_t)gr * DIM + gc] = tanh_fast(oc[r] + bias);
        }
    }
}

// ---------------------------------------------------------------- launch
extern "C" void kernel_launch(void* const* d_in, const int* in_sizes, int n_in,
                              void* d_out, int out_size, void* d_ws, size_t ws_size,
                              hipStream_t stream) {
    const float* node_feat = (const float*)d_in[0];
    const float* dyn_emb   = (const float*)d_in[1];
    const int*   src       = (const int*)  d_in[2];
    const int*   dst       = (const int*)  d_in[3];
    const int*   etypes    = (const int*)  d_in[4];
    const float* w1        = (const float*)d_in[5];
    const float* loop_w1   = (const float*)d_in[6];
    const float* b1        = (const float*)d_in[7];
    const float* w2        = (const float*)d_in[8];
    const float* loop_w2   = (const float*)d_in[9];
    const float* b2        = (const float*)d_in[10];
    const float* W_ih      = (const float*)d_in[11];
    const float* W_hh      = (const float*)d_in[12];
    const float* b_ih      = (const float*)d_in[13];
    const float* b_hh      = (const float*)d_in[14];
    float* out = (float*)d_out;

    // workspace layout (~72 MB)
    int*   degi = (int*)d_ws;                          // 51200
    int*   pos  = degi + 51200;                        // 51200
    int*   bsum = pos  + 51200;                        // 256
    int*   se   = bsum + 256;                          // 800000 int (3.2 MB)
    unsigned short* aggp = (unsigned short*)(se + N_EDGES);    // NROWPAD*KPAD bf16 (22.4 MB)
    unsigned short* hb   = aggp + (size_t)NROWPAD * KPAD;      // 22.4 MB — ALSO xb
    unsigned short* h0b  = hb   + (size_t)NROWPAD * KPAD;      // 22.4 MB
    unsigned short* w1f  = h0b  + (size_t)NROWPAD * KPAD;      // NFRAG8*8 each
    unsigned short* wihf = w1f  + (size_t)NFRAG8 * 8;
    unsigned short* whhf = wihf + (size_t)NFRAG8 * 8;
    unsigned short* Mf   = whhf + (size_t)NFRAG8 * 8;
    unsigned short* w1b  = Mf   + (size_t)NFRAG8 * 8;          // NRELS*NBLK*4 (184 KB)
    unsigned short* w2b  = w1b  + (size_t)NRELS * NBLK * 4;
    float* biasv = (float*)(w2b + (size_t)NRELS * NBLK * 4);   // KPN floats

    hipMemsetAsync(degi, 0, 51200 * sizeof(int), stream);

    // CSR build
    deg_int_kernel<<<(N_EDGES + 255) / 256, 256, 0, stream>>>(dst, degi);
    scanA<<<NB_SCAN, 256, 0, stream>>>(degi, pos, bsum);
    scanC2<<<NB_SCAN, 256, 0, stream>>>(pos, bsum);
    fill_kernel<<<(N_EDGES + 255) / 256, 256, 0, stream>>>(src, dst, etypes, pos, se);

    // prep (fused)
    prep_feat<<<(2 * NROWPAD * (KPAD / 2) + 255) / 256, 256, 0, stream>>>(
        node_feat, dyn_emb, hb, h0b);
    prep_wbs<<<(2 * NRELS * NBLK + 255) / 256, 256, 0, stream>>>(w1, w2, w1b, w2b);
    prep_frags<<<(3 * NFRAG8 + 255) / 256, 256, 0, stream>>>(
        loop_w1, W_ih, W_hh, w1f, wihf, whhf);
    prep_Mf<<<(NFRAG8 + KPN + 255) / 256, 256, 0, stream>>>(
        loop_w2, W_ih, b2, b_ih, b_hh, Mf, biasv);

    // ---- layer 1 (gather reads xb=hb; gemm1 overwrites it in place with h)
    gatherB<<<(N_NODES * 64 + 255) / 256, 256, 0, stream>>>(
        hb, se, pos, degi, w1b, aggp);
    gemm1_kernel<<<(N_NODES + 31) / 32, 256, 0, stream>>>(
        hb, aggp, b1, w1f);

    // ---- layer 2
    gatherB<<<(N_NODES * 64 + 255) / 256, 256, 0, stream>>>(
        hb, se, pos, degi, w2b, aggp);

    // ---- fused layer-2 dense + RNN cell (single phase via M = w2 @ W_ih^T)
    gemm2_kernel<<<(N_NODES + 31) / 32, 256, 0, stream>>>(
        hb, aggp, h0b, Mf, wihf, whhf, biasv, out);
}

// Round 11
// 338.577 us; speedup vs baseline: 1.0865x; 1.0865x over previous
//
#include <hip/hip_runtime.h>

#define N_NODES 50000
#define N_EDGES 800000
#define DIM     200
#define NBLK    100   // B blocks of S=2
#define NRELS   230
#define NB_SCAN 196   // ceil(N_NODES/256)
#define KPAD    224   // feature-row stride (bf16 buffers)
#define KPN     256   // gemm output-column pad (8 nt of 32)
#define NROWPAD 50048
#define NFRAG8  (8 * 14 * 64)   // fragment-packed weights: 8 nt x 14 ks x 64 lanes (x8 bf16)

typedef __attribute__((ext_vector_type(8)))  short short8;
typedef __attribute__((ext_vector_type(16))) float f32x16;

__device__ __forceinline__ unsigned short f2bf(float f) {
    unsigned u = __float_as_uint(f);
    u += 0x7fffu + ((u >> 16) & 1u);        // RNE (inputs finite)
    return (unsigned short)(u >> 16);
}

__device__ __forceinline__ float bflo(unsigned u) { return __uint_as_float(u << 16); }
__device__ __forceinline__ float bfhi(unsigned u) { return __uint_as_float(u & 0xffff0000u); }
__device__ __forceinline__ float b2f(unsigned short u) { return __uint_as_float((unsigned)u << 16); }

__device__ __forceinline__ float tanh_fast(float x) {
    float xa = fminf(fmaxf(x, -15.0f), 15.0f);
    float e = __expf(2.0f * xa);
    return (e - 1.0f) / (e + 1.0f);
}

__device__ __forceinline__ int uread(int v, int l) {
    return __builtin_amdgcn_readlane(v, l);
}

// ---- bf16 dot2: 1 instruction for a0*b0+a1*b1+c when available
#if __has_builtin(__builtin_amdgcn_fdot2_f32_bf16)
typedef __bf16 bf16x2 __attribute__((ext_vector_type(2)));
__device__ __forceinline__ float dot2bf(unsigned a, unsigned b, float c) {
    return __builtin_amdgcn_fdot2_f32_bf16(
        __builtin_bit_cast(bf16x2, a), __builtin_bit_cast(bf16x2, b), c, false);
}
#define CMP(XU, WU, M0, M1, M2, M3)                                     \
    { M0 = dot2bf(XU.x, WU.x, M0); M1 = dot2bf(XU.x, WU.y, M1);         \
      M2 = dot2bf(XU.y, WU.z, M2); M3 = dot2bf(XU.y, WU.w, M3); }
#else
#define CMP(XU, WU, M0, M1, M2, M3)                                     \
    { float x0 = bflo(XU.x), x1 = bfhi(XU.x);                           \
      float x2 = bflo(XU.y), x3 = bfhi(XU.y);                           \
      M0 += x0 * bflo(WU.x) + x1 * bfhi(WU.x);                          \
      M1 += x0 * bflo(WU.y) + x1 * bfhi(WU.y);                          \
      M2 += x2 * bflo(WU.z) + x3 * bfhi(WU.z);                          \
      M3 += x2 * bflo(WU.w) + x3 * bfhi(WU.w); }
#endif

// LDS swizzle for 512B-stride rows, 16B-granular access
#define SWZ5(rr, off) ((unsigned)((rr) * 512 + (off)) ^ ((unsigned)((rr) & 15) << 4))

// ---------------------------------------------------------------- CSR build
__global__ void deg_int_kernel(const int* __restrict__ dst, int* __restrict__ degi) {
    int e = blockIdx.x * blockDim.x + threadIdx.x;
    if (e < N_EDGES) atomicAdd(&degi[dst[e]], 1);
}

__global__ __launch_bounds__(256) void scanA(const int* __restrict__ degi,
                                             int* __restrict__ pos,
                                             int* __restrict__ bsum) {
    __shared__ int tmp[256];
    int t = threadIdx.x;
    int g = blockIdx.x * 256 + t;
    int v = (g < N_NODES) ? degi[g] : 0;
    tmp[t] = v;
    __syncthreads();
    for (int off = 1; off < 256; off <<= 1) {
        int xv = (t >= off) ? tmp[t - off] : 0;
        __syncthreads();
        tmp[t] += xv;
        __syncthreads();
    }
    if (g < N_NODES) pos[g] = tmp[t] - v;
    if (t == 255) bsum[blockIdx.x] = tmp[255];
}

// fused scanB+scanC: every block redundantly scans bsum (196 els), then adds its prefix
__global__ __launch_bounds__(256) void scanC2(int* __restrict__ pos, const int* __restrict__ bsum) {
    __shared__ int tmp[256];
    __shared__ int excl[256];
    int t = threadIdx.x;
    int v = (t < NB_SCAN) ? bsum[t] : 0;
    tmp[t] = v;
    __syncthreads();
    for (int off = 1; off < 256; off <<= 1) {
        int xv = (t >= off) ? tmp[t - off] : 0;
        __syncthreads();
        tmp[t] += xv;
        __syncthreads();
    }
    excl[t] = tmp[t] - v;
    __syncthreads();
    int add = excl[blockIdx.x];
    int g = blockIdx.x * 256 + t;
    if (g < N_NODES) pos[g] += add;
}

// fill: se[slot] = src | (etype << 16)
__global__ void fill_kernel(const int* __restrict__ src, const int* __restrict__ dst,
                            const int* __restrict__ et,
                            int* __restrict__ pos, int* __restrict__ se) {
    int e = blockIdx.x * blockDim.x + threadIdx.x;
    if (e < N_EDGES) {
        int d = dst[e];
        int slot = atomicAdd(&pos[d], 1);
        se[slot] = src[e] | (et[e] << 16);
    }
}

// ---------------------------------------------------------------- fused feature prep (node_feat->hb, dyn_emb->h0b)
__global__ void prep_feat(const float* __restrict__ x, const float* __restrict__ de,
                          unsigned short* __restrict__ hb, unsigned short* __restrict__ h0b) {
    const int HALF = NROWPAD * (KPAD / 2);
    int idx = blockIdx.x * blockDim.x + threadIdx.x;
    if (idx >= 2 * HALF) return;
    const float* src = (idx < HALF) ? x : de;
    unsigned short* dstp = (idx < HALF) ? hb : h0b;
    int j = (idx < HALF) ? idx : idx - HALF;
    int row = j / (KPAD / 2), cu = j % (KPAD / 2);
    unsigned pk = 0;
    if (row < N_NODES && cu < 100) {
        float2 v = *(const float2*)(src + (size_t)row * DIM + cu * 2);
        pk = (unsigned)f2bf(v.x) | ((unsigned)f2bf(v.y) << 16);
    }
    *(unsigned*)(dstp + (size_t)j * 2) = pk;
}

// fused relation-weight prep: w1->w1b, w2->w2b (dot2 column pairs)
__global__ void prep_wbs(const float* __restrict__ w1, const float* __restrict__ w2,
                         unsigned short* __restrict__ w1b, unsigned short* __restrict__ w2b) {
    const int HALF = NRELS * NBLK;
    int idx = blockIdx.x * blockDim.x + threadIdx.x;
    if (idx >= 2 * HALF) return;
    const float* w = (idx < HALF) ? w1 : w2;
    unsigned short* o = (idx < HALF) ? w1b : w2b;
    int j = (idx < HALF) ? idx : idx - HALF;
    float4 v = *(const float4*)(w + (size_t)j * 4);  // w00,w01,w10,w11
    unsigned c0 = (unsigned)f2bf(v.x) | ((unsigned)f2bf(v.z) << 16);
    unsigned c1 = (unsigned)f2bf(v.y) | ((unsigned)f2bf(v.w) << 16);
    *(uint2*)(o + (size_t)j * 4) = make_uint2(c0, c1);
}

// fused frag prep: sec0 = fragT(loop_w1)->w1f ; sec1 = frag(W_ih)->wihf ; sec2 = frag(W_hh)->whhf
__global__ void prep_frags(const float* __restrict__ lw1, const float* __restrict__ wih,
                           const float* __restrict__ whh,
                           unsigned short* __restrict__ w1f, unsigned short* __restrict__ wihf,
                           unsigned short* __restrict__ whhf) {
    int idx = blockIdx.x * blockDim.x + threadIdx.x;
    if (idx >= 3 * NFRAG8) return;
    int sec = idx / NFRAG8, f = idx % NFRAG8;
    const float* w = (sec == 0) ? lw1 : (sec == 1) ? wih : whh;
    unsigned short* o = (sec == 0) ? w1f : (sec == 1) ? wihf : whhf;
    int l = f & 63;
    int ks = (f >> 6) % 14;
    int nt = f / (14 * 64);
    int n  = nt * 32 + (l & 31);
    int k0 = ks * 16 + (l >> 5) * 8;
    unsigned short v[8];
    #pragma unroll
    for (int j = 0; j < 8; ++j) {
        int k = k0 + j;
        float val = 0.0f;
        if (n < DIM && k < DIM)
            val = (sec == 0) ? w[k * DIM + n] : w[n * DIM + k];
        v[j] = f2bf(val);
    }
    *(uint4*)(o + (size_t)f * 8) = *(uint4*)v;
}

// ---------------------------------------------------------------- M = w2 @ W_ih^T (parallel)
// Mt[(DIM+1) x DIM] f32: row k<DIM = sum_q w2[k][q]*wih[n][q]; row DIM = bias row:
//   dot(b2, wih[n]) + b_ih[n] + b_hh[n]
__global__ __launch_bounds__(256) void mcompute(
        const float* __restrict__ w2, const float* __restrict__ wih,
        const float* __restrict__ b2, const float* __restrict__ b_ih,
        const float* __restrict__ b_hh, float* __restrict__ Mt) {
    int idx = blockIdx.x * blockDim.x + threadIdx.x;
    if (idx >= (DIM + 1) * DIM) return;
    int k = idx / DIM, n = idx % DIM;
    const float* ar = (k < DIM) ? (w2 + (size_t)k * DIM) : b2;
    const float* br = wih + (size_t)n * DIM;
    float s0 = 0.f, s1 = 0.f, s2 = 0.f, s3 = 0.f;
    #pragma unroll 5
    for (int q = 0; q < DIM; q += 4) {
        float4 a = *(const float4*)(ar + q);
        float4 b = *(const float4*)(br + q);
        s0 += a.x * b.x; s1 += a.y * b.y; s2 += a.z * b.z; s3 += a.w * b.w;
    }
    float s = (s0 + s1) + (s2 + s3);
    if (k == DIM) s += b_ih[n] + b_hh[n];
    Mt[idx] = s;
}

// pack Mt -> fragment layout + biasv
__global__ void prep_Mf2(const float* __restrict__ Mt, unsigned short* __restrict__ Mf,
                         float* __restrict__ biasv) {
    int idx = blockIdx.x * blockDim.x + threadIdx.x;
    if (idx < NFRAG8) {
        int l = idx & 63;
        int ks = (idx >> 6) % 14;
        int nt = idx / (14 * 64);
        int n  = nt * 32 + (l & 31);
        int k0 = ks * 16 + (l >> 5) * 8;
        unsigned short v[8];
        #pragma unroll
        for (int j = 0; j < 8; ++j) {
            int k = k0 + j;
            v[j] = f2bf((n < DIM && k < DIM) ? Mt[k * DIM + n] : 0.0f);
        }
        *(uint4*)(Mf + (size_t)idx * 8) = *(uint4*)v;
    } else if (idx < NFRAG8 + KPN) {
        int n = idx - NFRAG8;
        biasv[n] = (n < DIM) ? Mt[DIM * DIM + n] : 0.0f;
    }
}

// ---------------------------------------------------------------- gather: 2 blocks/lane, 4-edge pipeline
// lane l<50 owns blocks {2l, 2l+1}; lanes 50-55 zero-fill pad cols 200..223 of agg.
#define GL(QQ, XU, WU)                                                  \
    { int p_ = uread(sv, (QQ)); int s_ = p_ & 0xffff; int r_ = p_ >> 16;\
      XU = *(const uint2*)(x  + (size_t)s_ * KPAD + xoff);              \
      WU = *(const uint4*)(wb + (size_t)r_ * (NBLK * 4) + woff); }

__global__ __launch_bounds__(256) void gatherB(
        const unsigned short* __restrict__ x,    // [NROWPAD][KPAD] bf16
        const int*   __restrict__ se,            // packed (src | et<<16), CSR order
        const int*   __restrict__ endpos,
        const int*   __restrict__ degi,
        const unsigned short* __restrict__ wb,   // [R][NBLK][4] bf16 (column pairs)
        unsigned short* __restrict__ agg) {      // [NROWPAD][KPAD] bf16
    int node = (blockIdx.x * blockDim.x + threadIdx.x) >> 6;
    int lane = threadIdx.x & 63;
    if (node >= N_NODES) return;
    int deg = __builtin_amdgcn_readfirstlane(degi[node]);
    const bool act = (lane < 50);
    int cl   = act ? lane : 49;                  // clamp idle lanes to valid addrs
    int xoff = 4 * cl;                           // ushort units (8B per lane)
    int woff = 8 * cl;                           // ushort units (16B per lane)

    if (deg == 0) {
        if (lane < 56) *(uint2*)(agg + (size_t)node * KPAD + 4 * lane) = make_uint2(0u, 0u);
        return;
    }
    int end   = __builtin_amdgcn_readfirstlane(endpos[node]);
    int start = end - deg;

    float m0A = 0.f, m1A = 0.f, m2A = 0.f, m3A = 0.f;
    float m0B = 0.f, m1B = 0.f, m2B = 0.f, m3B = 0.f;

    for (int base = start; base < end; base += 64) {
        int cnt = end - base; if (cnt > 64) cnt = 64;
        int sv = se[base + (lane < cnt ? lane : cnt - 1)];

        uint2 X0 = {0,0}, X1 = {0,0}, X2 = {0,0}, X3 = {0,0};
        uint4 W0 = {0,0,0,0}, W1 = {0,0,0,0}, W2 = {0,0,0,0}, W3 = {0,0,0,0};

        GL(0, X0, W0);
        if (cnt > 1) GL(1, X1, W1);
        if (cnt > 2) GL(2, X2, W2);

        for (int q = 0; q < cnt; q += 4) {
            if (q + 3 < cnt) GL(q + 3, X3, W3);
            CMP(X0, W0, m0A, m1A, m2A, m3A);
            if (q + 4 < cnt) GL(q + 4, X0, W0);
            if (q + 1 < cnt) CMP(X1, W1, m0B, m1B, m2B, m3B);
            if (q + 5 < cnt) GL(q + 5, X1, W1);
            if (q + 2 < cnt) CMP(X2, W2, m0A, m1A, m2A, m3A);
            if (q + 6 < cnt) GL(q + 6, X2, W2);
            if (q + 3 < cnt) CMP(X3, W3, m0B, m1B, m2B, m3B);
        }
    }
    float nrm = 1.0f / (float)deg;
    uint2 ov = make_uint2(0u, 0u);
    if (act) {
        ov.x = (unsigned)f2bf((m0A + m0B) * nrm) | ((unsigned)f2bf((m1A + m1B) * nrm) << 16);
        ov.y = (unsigned)f2bf((m2A + m2B) * nrm) | ((unsigned)f2bf((m3A + m3B) * nrm) << 16);
    }
    if (lane < 56) *(uint2*)(agg + (size_t)node * KPAD + 4 * lane) = ov;
}

// ---------------------------------------------------------------- GEMM1: hb = bf16(tanh(agg1 + x@loop_w1 + b1))
// In-place: xb and hb are the SAME buffer. agg1 is bf16 KPAD-strided.
__global__ __launch_bounds__(256) void gemm1_kernel(
        unsigned short* xb_hb,
        const unsigned short* __restrict__ agg1,  // [NROWPAD][KPAD] bf16
        const float* __restrict__ b1,
        const unsigned short* __restrict__ w1f) {
    __shared__ __align__(16) unsigned short s_a[32 * KPN];
    int row0 = blockIdx.x * 32;
    int tid = threadIdx.x;
    for (int i = tid; i < 32 * 32; i += 256) {
        int rr = i >> 5, ch = i & 31;
        uint4 v = {0, 0, 0, 0};
        if (ch < 28) v = *(const uint4*)(xb_hb + (size_t)(row0 + rr) * KPAD + ch * 8);
        *(uint4*)((char*)s_a + SWZ5(rr, ch * 16)) = v;
    }
    __syncthreads();

    int l = tid & 63, wv = tid >> 6;
    int rl = l & 31, hl = l >> 5;
    int ntlo = wv * 2;
    const unsigned short* wb = w1f + (size_t)(ntlo * 14) * 512 + l * 8;

    f32x16 acc0 = {}, acc1 = {};
    short8 aC  = *(const short8*)((const char*)s_a + SWZ5(rl, (hl * 8) * 2));
    short8 b0C = *(const short8*)(wb);
    short8 b1C = *(const short8*)(wb + 14 * 512);
    #pragma unroll
    for (int ks = 0; ks < 13; ++ks) {
        short8 aN = {}, b0N = {}, b1N = {};
        if (ks < 12) {
            aN  = *(const short8*)((const char*)s_a + SWZ5(rl, ((ks + 1) * 16 + hl * 8) * 2));
            b0N = *(const short8*)(wb + (ks + 1) * 512);
            b1N = *(const short8*)(wb + 14 * 512 + (ks + 1) * 512);
        }
        acc0 = __builtin_amdgcn_mfma_f32_32x32x16_bf16(aC, b0C, acc0, 0, 0, 0);
        acc1 = __builtin_amdgcn_mfma_f32_32x32x16_bf16(aC, b1C, acc1, 0, 0, 0);
        aC = aN; b0C = b0N; b1C = b1N;
    }
    __syncthreads();   // all tile reads done before in-place overwrite

    #pragma unroll
    for (int t = 0; t < 2; ++t) {
        f32x16 ac = t ? acc1 : acc0;
        int gc = (ntlo + t) * 32 + rl;
        if (gc >= KPAD) continue;
        float bias = (gc < DIM) ? b1[gc] : 0.0f;
        #pragma unroll
        for (int r = 0; r < 16; ++r) {
            int gr = row0 + (r & 3) + 8 * (r >> 2) + 4 * hl;
            float v = 0.0f;
            if (gc < DIM && gr < N_NODES)
                v = ac[r] + b2f(agg1[(size_t)gr * KPAD + gc]) + bias;
            xb_hb[(size_t)gr * KPAD + gc] = f2bf(tanh_fast(v));
        }
    }
}

// ---------------------------------------------------------------- GEMM2 single-phase:
// out = tanh( hb@M + agg2@W_ih^T + h0@W_hh^T + biasv )
__global__ __launch_bounds__(256) void gemm2_kernel(
        const unsigned short* __restrict__ hb,
        const unsigned short* __restrict__ aggp,  // [NROWPAD][KPAD] bf16
        const unsigned short* __restrict__ h0b,
        const unsigned short* __restrict__ Mf,    // frag-packed M (x@M), 8 nt
        const unsigned short* __restrict__ wihf,  // frag-packed W_ih (x@w^T), 8 nt
        const unsigned short* __restrict__ whhf,  // frag-packed W_hh (x@w^T), 8 nt
        const float* __restrict__ biasv,          // [KPN]
        float* __restrict__ out) {
    __shared__ __align__(16) unsigned short s_h[32 * KPN];
    __shared__ __align__(16) unsigned short s_g[32 * KPN];
    __shared__ __align__(16) unsigned short s_e[32 * KPN];
    int row0 = blockIdx.x * 32;
    int tid = threadIdx.x;
    for (int i = tid; i < 32 * 32; i += 256) {
        int rr = i >> 5, ch = i & 31;
        uint4 vh = {0,0,0,0}, vg = {0,0,0,0}, ve = {0,0,0,0};
        if (ch < 28) {
            size_t off = (size_t)(row0 + rr) * KPAD + ch * 8;
            vh = *(const uint4*)(hb   + off);
            vg = *(const uint4*)(aggp + off);
            ve = *(const uint4*)(h0b  + off);
        }
        unsigned sw = SWZ5(rr, ch * 16);
        *(uint4*)((char*)s_h + sw) = vh;
        *(uint4*)((char*)s_g + sw) = vg;
        *(uint4*)((char*)s_e + sw) = ve;
    }
    __syncthreads();

    int l = tid & 63, wv = tid >> 6;
    int rl = l & 31, hl = l >> 5;
    int ntlo = wv * 2;
    const unsigned short* pm = Mf   + (size_t)(ntlo * 14) * 512 + l * 8;
    const unsigned short* pi = wihf + (size_t)(ntlo * 14) * 512 + l * 8;
    const unsigned short* ph = whhf + (size_t)(ntlo * 14) * 512 + l * 8;

    f32x16 a0 = {}, a1 = {};
    unsigned off0 = SWZ5(rl, (hl * 8) * 2);
    short8 hC  = *(const short8*)((const char*)s_h + off0);
    short8 gC  = *(const short8*)((const char*)s_g + off0);
    short8 eC  = *(const short8*)((const char*)s_e + off0);
    short8 m0C = *(const short8*)(pm);
    short8 m1C = *(const short8*)(pm + 14 * 512);
    short8 i0C = *(const short8*)(pi);
    short8 i1C = *(const short8*)(pi + 14 * 512);
    short8 h0C = *(const short8*)(ph);
    short8 h1C = *(const short8*)(ph + 14 * 512);
    #pragma unroll
    for (int ks = 0; ks < 13; ++ks) {
        short8 hN = {}, gN = {}, eN = {};
        short8 m0N = {}, m1N = {}, i0N = {}, i1N = {}, h0N = {}, h1N = {};
        if (ks < 12) {
            unsigned off = SWZ5(rl, ((ks + 1) * 16 + hl * 8) * 2);
            hN  = *(const short8*)((const char*)s_h + off);
            gN  = *(const short8*)((const char*)s_g + off);
            eN  = *(const short8*)((const char*)s_e + off);
            m0N = *(const short8*)(pm + (ks + 1) * 512);
            m1N = *(const short8*)(pm + 14 * 512 + (ks + 1) * 512);
            i0N = *(const short8*)(pi + (ks + 1) * 512);
            i1N = *(const short8*)(pi + 14 * 512 + (ks + 1) * 512);
            h0N = *(const short8*)(ph + (ks + 1) * 512);
            h1N = *(const short8*)(ph + 14 * 512 + (ks + 1) * 512);
        }
        a0 = __builtin_amdgcn_mfma_f32_32x32x16_bf16(hC, m0C, a0, 0, 0, 0);
        a0 = __builtin_amdgcn_mfma_f32_32x32x16_bf16(gC, i0C, a0, 0, 0, 0);
        a0 = __builtin_amdgcn_mfma_f32_32x32x16_bf16(eC, h0C, a0, 0, 0, 0);
        a1 = __builtin_amdgcn_mfma_f32_32x32x16_bf16(hC, m1C, a1, 0, 0, 0);
        a1 = __builtin_amdgcn_mfma_f32_32x32x16_bf16(gC, i1C, a1, 0, 0, 0);
        a1 = __builtin_amdgcn_mfma_f32_32x32x16_bf16(eC, h1C, a1, 0, 0, 0);
        hC = hN; gC = gN; eC = eN;
        m0C = m0N; m1C = m1N; i0C = i0N; i1C = i1N; h0C = h0N; h1C = h1N;
    }

    #pragma unroll
    for (int t = 0; t < 2; ++t) {
        f32x16 oc = t ? a1 : a0;
        int gc = (ntlo + t) * 32 + rl;
        if (gc >= DIM) continue;
        float bias = biasv[gc];
        #pragma unroll
        for (int r = 0; r < 16; ++r) {
            int gr = row0 + (r & 3) + 8 * (r >> 2) + 4 * hl;
            if (gr < N_NODES)
                out[(size_t)gr * DIM + gc] = tanh_fast(oc[r] + bias);
        }
    }
}

// ---------------------------------------------------------------- launch
extern "C" void kernel_launch(void* const* d_in, const int* in_sizes, int n_in,
                              void* d_out, int out_size, void* d_ws, size_t ws_size,
                              hipStream_t stream) {
    const float* node_feat = (const float*)d_in[0];
    const float* dyn_emb   = (const float*)d_in[1];
    const int*   src       = (const int*)  d_in[2];
    const int*   dst       = (const int*)  d_in[3];
    const int*   etypes    = (const int*)  d_in[4];
    const float* w1        = (const float*)d_in[5];
    const float* loop_w1   = (const float*)d_in[6];
    const float* b1        = (const float*)d_in[7];
    const float* w2        = (const float*)d_in[8];
    const float* loop_w2   = (const float*)d_in[9];
    const float* b2        = (const float*)d_in[10];
    const float* W_ih      = (const float*)d_in[11];
    const float* W_hh      = (const float*)d_in[12];
    const float* b_ih      = (const float*)d_in[13];
    const float* b_hh      = (const float*)d_in[14];
    float* out = (float*)d_out;

    // workspace layout (~72 MB)
    int*   degi = (int*)d_ws;                          // 51200
    int*   pos  = degi + 51200;                        // 51200
    int*   bsum = pos  + 51200;                        // 256
    int*   se   = bsum + 256;                          // 800000 int (3.2 MB)
    unsigned short* aggp = (unsigned short*)(se + N_EDGES);    // NROWPAD*KPAD bf16 (22.4 MB)
    unsigned short* hb   = aggp + (size_t)NROWPAD * KPAD;      // 22.4 MB — ALSO xb
    unsigned short* h0b  = hb   + (size_t)NROWPAD * KPAD;      // 22.4 MB
    unsigned short* w1f  = h0b  + (size_t)NROWPAD * KPAD;      // NFRAG8*8 each
    unsigned short* wihf = w1f  + (size_t)NFRAG8 * 8;
    unsigned short* whhf = wihf + (size_t)NFRAG8 * 8;
    unsigned short* Mf   = whhf + (size_t)NFRAG8 * 8;
    unsigned short* w1b  = Mf   + (size_t)NFRAG8 * 8;          // NRELS*NBLK*4 (184 KB)
    unsigned short* w2b  = w1b  + (size_t)NRELS * NBLK * 4;
    float* biasv = (float*)(w2b + (size_t)NRELS * NBLK * 4);   // KPN floats
    float* Mt    = biasv + KPN;                                // (DIM+1)*DIM floats

    hipMemsetAsync(degi, 0, 51200 * sizeof(int), stream);

    // CSR build
    deg_int_kernel<<<(N_EDGES + 255) / 256, 256, 0, stream>>>(dst, degi);
    scanA<<<NB_SCAN, 256, 0, stream>>>(degi, pos, bsum);
    scanC2<<<NB_SCAN, 256, 0, stream>>>(pos, bsum);
    fill_kernel<<<(N_EDGES + 255) / 256, 256, 0, stream>>>(src, dst, etypes, pos, se);

    // prep (fused)
    prep_feat<<<(2 * NROWPAD * (KPAD / 2) + 255) / 256, 256, 0, stream>>>(
        node_feat, dyn_emb, hb, h0b);
    prep_wbs<<<(2 * NRELS * NBLK + 255) / 256, 256, 0, stream>>>(w1, w2, w1b, w2b);
    prep_frags<<<(3 * NFRAG8 + 255) / 256, 256, 0, stream>>>(
        loop_w1, W_ih, W_hh, w1f, wihf, whhf);
    mcompute<<<((DIM + 1) * DIM + 255) / 256, 256, 0, stream>>>(
        loop_w2, W_ih, b2, b_ih, b_hh, Mt);
    prep_Mf2<<<(NFRAG8 + KPN + 255) / 256, 256, 0, stream>>>(Mt, Mf, biasv);

    // ---- layer 1 (gather reads xb=hb; gemm1 overwrites it in place with h)
    gatherB<<<(N_NODES * 64 + 255) / 256, 256, 0, stream>>>(
        hb, se, pos, degi, w1b, aggp);
    gemm1_kernel<<<(N_NODES + 31) / 32, 256, 0, stream>>>(
        hb, aggp, b1, w1f);

    // ---- layer 2
    gatherB<<<(N_NODES * 64 + 255) / 256, 256, 0, stream>>>(
        hb, se, pos, degi, w2b, aggp);

    // ---- fused layer-2 dense + RNN cell (single phase via M = w2 @ W_ih^T)
    gemm2_kernel<<<(N_NODES + 31) / 32, 256, 0, stream>>>(
        hb, aggp, h0b, Mf, wihf, whhf, biasv, out);
}